// Round 1
// 289.491 us; speedup vs baseline: 1.1455x; 1.1455x over previous
//
#include <hip/hip_runtime.h>

typedef unsigned int uint;
typedef unsigned short ushort;
typedef float f32x4 __attribute__((ext_vector_type(4)));
typedef float f32x16 __attribute__((ext_vector_type(16)));
typedef short bf16x8 __attribute__((ext_vector_type(8)));

#define SQ_   2048
#define SK_   2048
#define NB    8
#define DD    1024
#define INNER 128
#define H_    4
#define HD    32
// (1/sqrt(32)) * log2(e), folded into Wq during wprep; attention computes 2^s
// directly with v_exp_f32 (softmax ratio is invariant to the base change).
#define ALPHA (0.17677669529663687f * 1.4426950408889634f)
#define PROW  136   // LDS X row: 128 bf16 + 8 pad (bank-uniform for b128 r/w)

__device__ __forceinline__ ushort f2bf(float f) {
    uint u = __float_as_uint(f);
    u += 0x7fffu + ((u >> 16) & 1u);
    return (ushort)(u >> 16);
}
__device__ __forceinline__ uint pack2(float a, float b) {
    return (uint)f2bf(a) | ((uint)f2bf(b) << 16);
}
// HW packed f32->bf16 (RNE), 1 instr instead of ~9.
__device__ __forceinline__ uint cvtpk(float a, float b) {
    uint r;
    asm("v_cvt_pk_bf16_f32 %0, %1, %2" : "=v"(r) : "v"(a), "v"(b));
    return r;
}
__device__ __forceinline__ float fexp2(float x) {
    float r;
    asm("v_exp_f32 %0, %1" : "=v"(r) : "v"(x));
    return r;
}
// v_permlane32_swap_b32: vdst[32:63] <-> vsrc[0:31] (2x32 transpose semantics).
// After: a = {a_lo, b_lo}, b = {a_hi, b_hi}.
__device__ __forceinline__ void plswap(uint &a, uint &b) {
#if __has_builtin(__builtin_amdgcn_permlane32_swap)
    auto r = __builtin_amdgcn_permlane32_swap(a, b, false, false);
    a = (uint)r[0];
    b = (uint)r[1];
#else
    asm("v_permlane32_swap_b32 %0, %1" : "+v"(a), "+v"(b));
#endif
}

// ---------------------------------------------------------------------------
// Kernel 0: convert Wq/Wk/Wv -> wbf (ALPHA folded into Wq) and Wup -> wup_bf.
// ---------------------------------------------------------------------------
__global__ __launch_bounds__(256) void wprep_kernel(
    const float* __restrict__ Wq, const float* __restrict__ Wk,
    const float* __restrict__ Wv, const float* __restrict__ Wup,
    ushort* __restrict__ wbf, ushort* __restrict__ wup_bf)
{
    int idx = (blockIdx.x * 256 + threadIdx.x) * 8;
    const float* W;
    ushort* dst;
    float sc = 1.0f;
    int off;
    if (idx < 393216) {
        int which = idx >> 17;                   // /131072
        off = idx & 131071;
        W = (which == 0) ? Wq : (which == 1) ? Wk : Wv;
        if (which == 0) sc = ALPHA;
        dst = wbf + idx;
    } else {
        off = idx - 393216;
        W = Wup;
        dst = wup_bf + off;
    }
    float4 a = *(const float4*)(W + off);
    float4 b = *(const float4*)(W + off + 4);
    uint4 o;
    o.x = pack2(a.x * sc, a.y * sc);
    o.y = pack2(a.z * sc, a.w * sc);
    o.z = pack2(b.x * sc, b.y * sc);
    o.w = pack2(b.z * sc, b.w * sc);
    *(uint4*)dst = o;
}

// ---------------------------------------------------------------------------
// Kernel 1: QKV projection via MFMA 16x16x32 bf16 (unchanged).
// Output: dst[((n*H+h)*2048+s)*32+c] bf16, p = s*8+n.
// ---------------------------------------------------------------------------
__global__ __launch_bounds__(256) void proj_mfma(
    const float* __restrict__ query, const float* __restrict__ key_feat,
    const ushort* __restrict__ wbf,
    ushort* __restrict__ q_ws, ushort* __restrict__ k_ws, ushort* __restrict__ v_ws)
{
    const int which = blockIdx.y;
    const float* src = (which == 0) ? query : key_feat;
    const ushort* W  = wbf + (size_t)which * (INNER * DD);
    ushort* dst      = (which == 0) ? q_ws : (which == 1) ? k_ws : v_ws;

    __shared__ ushort Xs[64 * PROW];             // 17408 B

    const int pblk = blockIdx.x;
    const int t = threadIdx.x;
    const int wave = t >> 6, lane = t & 63, quad = lane >> 4, col = lane & 15;

    const int sp = t >> 2, sq = t & 3;
    const float* srow = src + (size_t)(pblk * 64 + sp) * DD + sq * 32;
    ushort* lrow = Xs + sp * PROW + sq * 32;

    f32x4 acc[2][4];
#pragma unroll
    for (int e = 0; e < 2; e++)
#pragma unroll
        for (int pt = 0; pt < 4; pt++) acc[e][pt] = (f32x4){0.f, 0.f, 0.f, 0.f};

    const ushort* wrow0 = W + (size_t)(32 * wave + col) * DD + quad * 8;
    const ushort* wrow1 = W + (size_t)(32 * wave + 16 + col) * DD + quad * 8;

    for (int slab = 0; slab < DD / 128; slab++) {
        const float4* g = (const float4*)(srow + slab * 128);
        float4 f0 = g[0], f1 = g[1], f2 = g[2], f3 = g[3];
        float4 f4 = g[4], f5 = g[5], f6 = g[6], f7 = g[7];
        __syncthreads();                         // prior slab's reads done
        uint4 u;
        u.x = pack2(f0.x, f0.y); u.y = pack2(f0.z, f0.w);
        u.z = pack2(f1.x, f1.y); u.w = pack2(f1.z, f1.w);
        *(uint4*)(lrow) = u;
        u.x = pack2(f2.x, f2.y); u.y = pack2(f2.z, f2.w);
        u.z = pack2(f3.x, f3.y); u.w = pack2(f3.z, f3.w);
        *(uint4*)(lrow + 8) = u;
        u.x = pack2(f4.x, f4.y); u.y = pack2(f4.z, f4.w);
        u.z = pack2(f5.x, f5.y); u.w = pack2(f5.z, f5.w);
        *(uint4*)(lrow + 16) = u;
        u.x = pack2(f6.x, f6.y); u.y = pack2(f6.z, f6.w);
        u.z = pack2(f7.x, f7.y); u.w = pack2(f7.z, f7.w);
        *(uint4*)(lrow + 24) = u;
        __syncthreads();

#pragma unroll
        for (int kk = 0; kk < 4; kk++) {
            bf16x8 aW0 = *(const bf16x8*)(wrow0 + slab * 128 + kk * 32);
            bf16x8 aW1 = *(const bf16x8*)(wrow1 + slab * 128 + kk * 32);
#pragma unroll
            for (int pt = 0; pt < 4; pt++) {
                bf16x8 bX = *(const bf16x8*)(Xs + (pt * 16 + col) * PROW + kk * 32 + quad * 8);
                acc[0][pt] = __builtin_amdgcn_mfma_f32_16x16x32_bf16(aW0, bX, acc[0][pt], 0, 0, 0);
                acc[1][pt] = __builtin_amdgcn_mfma_f32_16x16x32_bf16(aW1, bX, acc[1][pt], 0, 0, 0);
            }
        }
    }

#pragma unroll
    for (int pt = 0; pt < 4; pt++) {
        int p = pblk * 64 + pt * 16 + col;
        int s = p >> 3, n = p & 7;
        ushort* base = dst + ((size_t)(n * H_ + wave) * 2048 + s) * HD;
#pragma unroll
        for (int e = 0; e < 2; e++) {
            uint2 pk;
            pk.x = pack2(acc[e][pt][0], acc[e][pt][1]);
            pk.y = pack2(acc[e][pt][2], acc[e][pt][3]);
            *(uint2*)(base + e * 16 + quad * 4) = pk;
        }
    }
}

// ---------------------------------------------------------------------------
// Kernel 2: transpose V -> V^T.  v_ws[nh][key][32] bf16 -> vt_ws[nh][32][key].
// ---------------------------------------------------------------------------
__global__ __launch_bounds__(256) void vtrans_kernel(
    const ushort* __restrict__ v_ws, ushort* __restrict__ vt_ws)
{
    const int nh = blockIdx.x >> 4;
    const int slab = blockIdx.x & 15;
    __shared__ ushort t[HD][132];            // +4 pad
    const uint* src = (const uint*)(v_ws + ((size_t)nh * SK_ + slab * 128) * HD);
#pragma unroll
    for (int it = 0; it < 8; it++) {
        int i = it * 256 + threadIdx.x;      // 2048 uints = 128 keys x 16
        int key = i >> 4, j = i & 15;
        uint u = src[i];
        t[2 * j][key]     = (ushort)(u & 0xffffu);
        t[2 * j + 1][key] = (ushort)(u >> 16);
    }
    __syncthreads();
    uint* dst = (uint*)vt_ws;
#pragma unroll
    for (int it = 0; it < 8; it++) {
        int i = it * 256 + threadIdx.x;      // 2048 uints = 32 c x 64
        int c = i >> 6, kk = (i & 63) * 2;
        dst[(size_t)(nh * HD + c) * (SK_ / 2) + slab * 64 + (i & 63)] =
            (uint)t[c][kk] | ((uint)t[c][kk + 1] << 16);
    }
}

// ---------------------------------------------------------------------------
// Kernel 3: attention via MFMA 32x32x16 bf16 (T12 restructure).
// Wave tile = 32 q x 32 k.  Swapped QK^T: lane holds P[key=crow(r,hi)][q=lane&31].
// P -> PV B-frag via 8 cvt_pk + 4 permlane32_swap (replaces pack2+8 bpermute).
// K split across wave pairs (unnormalized exp is distributive); LDS combine.
// ---------------------------------------------------------------------------
__global__ __launch_bounds__(256) void attn_mfma(
    const ushort* __restrict__ q_ws, const ushort* __restrict__ k_ws,
    const ushort* __restrict__ vt_ws, ushort* __restrict__ x_ws)
{
    const int nh    = blockIdx.y;
    const int lane  = threadIdx.x & 63;
    const int wave  = threadIdx.x >> 6;
    const int tile  = wave >> 1;         // which 32-q tile of the block's 64
    const int khalf = wave & 1;          // [0,1024) or [1024,2048) keys
    const int row   = lane & 31;
    const int hi    = lane >> 5;
    const int qbase = blockIdx.x * 64 + tile * 32;

    // B-frag Q: lane holds Q[hd=hi*8+j][q=qbase+row], contiguous 16B loads.
    const ushort* qrow = q_ws + ((size_t)nh * SQ_ + qbase + row) * HD;
    const bf16x8 bQ0 = *(const bf16x8*)(qrow + hi * 8);
    const bf16x8 bQ1 = *(const bf16x8*)(qrow + 16 + hi * 8);

    const ushort* kb = k_ws  + (size_t)nh * SK_ * HD + (size_t)row * HD + hi * 8;
    const ushort* vb = vt_ws + (size_t)nh * HD * SK_ + (size_t)row * SK_ + hi * 8;

    f32x16 acc = {};
    float lsum = 0.f;

    const int kc0 = khalf * (SK_ / 2);
#pragma unroll 2
    for (int kc = kc0; kc < kc0 + SK_ / 2; kc += 32) {
        // A-frag K rows (keys kc+row, hd split by hi), A-frag V^T rows (c=row).
        bf16x8 aK0 = *(const bf16x8*)(kb + (size_t)kc * HD);
        bf16x8 aK1 = *(const bf16x8*)(kb + (size_t)kc * HD + 16);
        bf16x8 aV0 = *(const bf16x8*)(vb + kc);
        bf16x8 aV1 = *(const bf16x8*)(vb + kc + 16);

        f32x16 S = {};
        S = __builtin_amdgcn_mfma_f32_32x32x16_bf16(aK0, bQ0, S, 0, 0, 0);
        S = __builtin_amdgcn_mfma_f32_32x32x16_bf16(aK1, bQ1, S, 0, 0, 0);

        // P[key][q] = 2^S  (log2e folded into Wq).  reg r -> key (r&3)+8*(r>>2)+4*hi.
        float p[16];
#pragma unroll
        for (int r = 0; r < 16; r++) p[r] = fexp2(S[r]);

        lsum += ((((p[0] + p[1]) + (p[2] + p[3])) + ((p[4] + p[5]) + (p[6] + p[7])))
               + (((p[8] + p[9]) + (p[10] + p[11])) + ((p[12] + p[13]) + (p[14] + p[15]))));

        // Build PV B-frags: word jw of frag needs keys (hi*8+2jw, hi*8+2jw+1).
        uint w0 = cvtpk(p[0], p[1]),   w2 = cvtpk(p[4], p[5]);
        uint w1 = cvtpk(p[2], p[3]),   w3 = cvtpk(p[6], p[7]);
        plswap(w0, w2);                // w0={lo(0,1),hi(8,9)}  w2={lo(4,5),hi(12,13)}
        plswap(w1, w3);                // w1={lo(2,3),hi(10,11)} w3={lo(6,7),hi(14,15)}
        uint w4 = cvtpk(p[8], p[9]),   w6 = cvtpk(p[12], p[13]);
        uint w5 = cvtpk(p[10], p[11]), w7 = cvtpk(p[14], p[15]);
        plswap(w4, w6);
        plswap(w5, w7);
        bf16x8 bP0 = __builtin_bit_cast(bf16x8, make_uint4(w0, w1, w2, w3));
        bf16x8 bP1 = __builtin_bit_cast(bf16x8, make_uint4(w4, w5, w6, w7));

        acc = __builtin_amdgcn_mfma_f32_32x32x16_bf16(aV0, bP0, acc, 0, 0, 0);
        acc = __builtin_amdgcn_mfma_f32_32x32x16_bf16(aV1, bP1, acc, 0, 0, 0);
    }

    // Combine the two K-halves (wave pairs) via LDS, then normalize + store.
    __shared__ float red[2][16][64];     // [tile][reg][lane] - conflict-free
    __shared__ float redl[2][64];
    if (khalf) {
#pragma unroll
        for (int r = 0; r < 16; r++) red[tile][r][lane] = acc[r];
        redl[tile][lane] = lsum;
    }
    __syncthreads();
    if (!khalf) {
#pragma unroll
        for (int r = 0; r < 16; r++) acc[r] += red[tile][r][lane];
        lsum += redl[tile][lane];
        lsum += __shfl_xor(lsum, 32, 64);   // lanes l, l^32 hold complementary keys
        const float inv = 1.f / lsum;

        const int n = nh >> 2, h = nh & 3;
        ushort* xo = x_ws + ((size_t)n * SQ_ + qbase + row) * INNER + h * HD;
#pragma unroll
        for (int rg = 0; rg < 4; rg++) {    // acc reg rg*4+t -> c = t + 8*rg + 4*hi
            uint2 pk;
            pk.x = cvtpk(acc[rg * 4 + 0] * inv, acc[rg * 4 + 1] * inv);
            pk.y = cvtpk(acc[rg * 4 + 2] * inv, acc[rg * 4 + 3] * inv);
            *(uint2*)(xo + rg * 8 + hi * 4) = pk;
        }
    }
}

// ---------------------------------------------------------------------------
// Kernel 4: up-projection via MFMA 16x16x32 bf16 (unchanged).
// ---------------------------------------------------------------------------
__global__ __launch_bounds__(256) void up_mfma(
    const ushort* __restrict__ x_ws, const ushort* __restrict__ wup_bf,
    float* __restrict__ out)
{
    const int pblk = blockIdx.x;
    const int dblk = blockIdx.y;
    const int wave = threadIdx.x >> 6, lane = threadIdx.x & 63;
    const int quad = lane >> 4, col = lane & 15;

    const int p0 = pblk * 64 + wave * 16;
    const ushort* xrow = x_ws + (size_t)(p0 + col) * INNER + quad * 8;
    bf16x8 bX[4];
#pragma unroll
    for (int kk = 0; kk < 4; kk++)
        bX[kk] = *(const bf16x8*)(xrow + kk * 32);

    const int p = p0 + col;
    const int n = p >> 11, s = p & 2047;        // x row p = n*2048 + s
    float* obase = out + ((size_t)s * NB + n) * DD;

#pragma unroll
    for (int mt = 0; mt < 4; mt++) {
        const int d0 = dblk * 64 + mt * 16;
        const ushort* wrow = wup_bf + (size_t)(d0 + col) * INNER + quad * 8;
        f32x4 acc = {0.f, 0.f, 0.f, 0.f};
#pragma unroll
        for (int kk = 0; kk < 4; kk++) {
            bf16x8 aW = *(const bf16x8*)(wrow + kk * 32);
            acc = __builtin_amdgcn_mfma_f32_16x16x32_bf16(aW, bX[kk], acc, 0, 0, 0);
        }
        *(float4*)(obase + d0 + quad * 4) = make_float4(acc[0], acc[1], acc[2], acc[3]);
    }
}

// ---------------------------------------------------------------------------
extern "C" void kernel_launch(void* const* d_in, const int* in_sizes, int n_in,
                              void* d_out, int out_size, void* d_ws, size_t ws_size,
                              hipStream_t stream)
{
    const float* query    = (const float*)d_in[0];
    const float* key_feat = (const float*)d_in[1];
    const float* Wq  = (const float*)d_in[2];
    const float* Wk  = (const float*)d_in[3];
    const float* Wv  = (const float*)d_in[4];
    const float* Wup = (const float*)d_in[5];
    float* out = (float*)d_out;

    ushort* ws16 = (ushort*)d_ws;
    const size_t SZ = (size_t)NB * H_ * 2048 * HD;   // 2,097,152 elems per tensor
    ushort* q_ws   = ws16;                           // bf16
    ushort* k_ws   = ws16 + SZ;                      // bf16
    ushort* v_ws   = ws16 + 2 * SZ;                  // bf16
    ushort* vt_ws  = ws16 + 3 * SZ;                  // bf16, transposed
    ushort* wbf    = vt_ws;                          // aliased: consumed by proj
                                                     // BEFORE vtrans overwrites
    ushort* x_ws   = ws16 + 4 * SZ;                  // bf16
    ushort* wup_bf = ws16 + 5 * SZ;                  // bf16, never aliased

    wprep_kernel<<<256, 256, 0, stream>>>(Wq, Wk, Wv, Wup, wbf, wup_bf);
    proj_mfma<<<dim3(256, 3), 256, 0, stream>>>(query, key_feat, wbf,
                                                q_ws, k_ws, v_ws);
    vtrans_kernel<<<512, 256, 0, stream>>>(v_ws, vt_ws);
    attn_mfma<<<dim3(SQ_ / 64, 32), 256, 0, stream>>>(q_ws, k_ws, vt_ws, x_ws);
    up_mfma<<<dim3(256, 16), 256, 0, stream>>>(x_ws, wup_bf, out);
}

// Round 2
// 286.157 us; speedup vs baseline: 1.1589x; 1.0117x over previous
//
#include <hip/hip_runtime.h>

typedef unsigned int uint;
typedef unsigned short ushort;
typedef float f32x4 __attribute__((ext_vector_type(4)));
typedef float f32x16 __attribute__((ext_vector_type(16)));
typedef short bf16x8 __attribute__((ext_vector_type(8)));

#define SQ_   2048
#define SK_   2048
#define NB    8
#define DD    1024
#define INNER 128
#define H_    4
#define HD    32
// (1/sqrt(32)) * log2(e), folded into Wq during wprep; attention computes 2^s
// directly with v_exp_f32 (softmax ratio is invariant to the base change).
#define ALPHA (0.17677669529663687f * 1.4426950408889634f)
#define PROW  136   // LDS X row: 128 bf16 + 8 pad (bank-uniform for b128 r/w)

__device__ __forceinline__ ushort f2bf(float f) {
    uint u = __float_as_uint(f);
    u += 0x7fffu + ((u >> 16) & 1u);
    return (ushort)(u >> 16);
}
__device__ __forceinline__ uint pack2(float a, float b) {
    return (uint)f2bf(a) | ((uint)f2bf(b) << 16);
}
// HW packed f32->bf16 (RNE), 1 instr instead of ~7.
__device__ __forceinline__ uint cvtpk(float a, float b) {
    uint r;
    asm("v_cvt_pk_bf16_f32 %0, %1, %2" : "=v"(r) : "v"(a), "v"(b));
    return r;
}
__device__ __forceinline__ float fexp2(float x) {
    float r;
    asm("v_exp_f32 %0, %1" : "=v"(r) : "v"(x));
    return r;
}
// v_permlane32_swap_b32: vdst[32:63] <-> vsrc[0:31] (2x32 transpose semantics).
__device__ __forceinline__ void plswap(uint &a, uint &b) {
#if __has_builtin(__builtin_amdgcn_permlane32_swap)
    auto r = __builtin_amdgcn_permlane32_swap(a, b, false, false);
    a = (uint)r[0];
    b = (uint)r[1];
#else
    asm("v_permlane32_swap_b32 %0, %1" : "+v"(a), "+v"(b));
#endif
}

// ---------------------------------------------------------------------------
// Kernel 0: convert Wq/Wk/Wv -> wbf (ALPHA folded into Wq) and Wup -> wup_bf.
// ---------------------------------------------------------------------------
__global__ __launch_bounds__(256) void wprep_kernel(
    const float* __restrict__ Wq, const float* __restrict__ Wk,
    const float* __restrict__ Wv, const float* __restrict__ Wup,
    ushort* __restrict__ wbf, ushort* __restrict__ wup_bf)
{
    int idx = (blockIdx.x * 256 + threadIdx.x) * 8;
    const float* W;
    ushort* dst;
    float sc = 1.0f;
    int off;
    if (idx < 393216) {
        int which = idx >> 17;                   // /131072
        off = idx & 131071;
        W = (which == 0) ? Wq : (which == 1) ? Wk : Wv;
        if (which == 0) sc = ALPHA;
        dst = wbf + idx;
    } else {
        off = idx - 393216;
        W = Wup;
        dst = wup_bf + off;
    }
    float4 a = *(const float4*)(W + off);
    float4 b = *(const float4*)(W + off + 4);
    uint4 o;
    o.x = pack2(a.x * sc, a.y * sc);
    o.y = pack2(a.z * sc, a.w * sc);
    o.z = pack2(b.x * sc, b.y * sc);
    o.w = pack2(b.z * sc, b.w * sc);
    *(uint4*)dst = o;
}

// ---------------------------------------------------------------------------
// Kernel 1: QKV projection via MFMA 16x16x32 bf16.
// Round-7 pipeline: double-buffered LDS X-tile (one barrier per slab),
// register prefetch of slab k+1 issued after the barrier (hides HBM latency
// under the MFMA phase; not drained since the next vmcnt(0)-barrier comes
// after the consuming pack), and HW v_cvt_pk_bf16_f32 packing.
// Output: dst[((n*H+h)*2048+s)*32+c] bf16, p = s*8+n.
// ---------------------------------------------------------------------------
__global__ __launch_bounds__(256) void proj_mfma(
    const float* __restrict__ query, const float* __restrict__ key_feat,
    const ushort* __restrict__ wbf,
    ushort* __restrict__ q_ws, ushort* __restrict__ k_ws, ushort* __restrict__ v_ws)
{
    const int which = blockIdx.y;
    const float* src = (which == 0) ? query : key_feat;
    const ushort* W  = wbf + (size_t)which * (INNER * DD);
    ushort* dst      = (which == 0) ? q_ws : (which == 1) ? k_ws : v_ws;

    __shared__ ushort Xs[2][64 * PROW];          // 34816 B total

    const int pblk = blockIdx.x;
    const int t = threadIdx.x;
    const int wave = t >> 6, lane = t & 63, quad = lane >> 4, col = lane & 15;

    const int sp = t >> 2, sq = t & 3;
    const float* srow = src + (size_t)(pblk * 64 + sp) * DD + sq * 32;

    f32x4 acc[2][4];
#pragma unroll
    for (int e = 0; e < 2; e++)
#pragma unroll
        for (int pt = 0; pt < 4; pt++) acc[e][pt] = (f32x4){0.f, 0.f, 0.f, 0.f};

    const ushort* wrow0 = W + (size_t)(32 * wave + col) * DD + quad * 8;
    const ushort* wrow1 = W + (size_t)(32 * wave + 16 + col) * DD + quad * 8;

    // prefetch slab 0
    float4 f[8];
    {
        const float4* g = (const float4*)srow;
#pragma unroll
        for (int i = 0; i < 8; i++) f[i] = g[i];
    }

#pragma unroll 2
    for (int slab = 0; slab < DD / 128; slab++) {
        ushort* lrow = Xs[slab & 1] + sp * PROW + sq * 32;
        uint4 u;
        u.x = cvtpk(f[0].x, f[0].y); u.y = cvtpk(f[0].z, f[0].w);
        u.z = cvtpk(f[1].x, f[1].y); u.w = cvtpk(f[1].z, f[1].w);
        *(uint4*)(lrow) = u;
        u.x = cvtpk(f[2].x, f[2].y); u.y = cvtpk(f[2].z, f[2].w);
        u.z = cvtpk(f[3].x, f[3].y); u.w = cvtpk(f[3].z, f[3].w);
        *(uint4*)(lrow + 8) = u;
        u.x = cvtpk(f[4].x, f[4].y); u.y = cvtpk(f[4].z, f[4].w);
        u.z = cvtpk(f[5].x, f[5].y); u.w = cvtpk(f[5].z, f[5].w);
        *(uint4*)(lrow + 16) = u;
        u.x = cvtpk(f[6].x, f[6].y); u.y = cvtpk(f[6].z, f[6].w);
        u.z = cvtpk(f[7].x, f[7].y); u.w = cvtpk(f[7].z, f[7].w);
        *(uint4*)(lrow + 24) = u;
        __syncthreads();

        // prefetch next slab (issued before MFMA phase; consumed next iter)
        if (slab < DD / 128 - 1) {
            const float4* g = (const float4*)(srow + (slab + 1) * 128);
#pragma unroll
            for (int i = 0; i < 8; i++) f[i] = g[i];
        }

        const ushort* xb = Xs[slab & 1];
#pragma unroll
        for (int kk = 0; kk < 4; kk++) {
            bf16x8 aW0 = *(const bf16x8*)(wrow0 + slab * 128 + kk * 32);
            bf16x8 aW1 = *(const bf16x8*)(wrow1 + slab * 128 + kk * 32);
#pragma unroll
            for (int pt = 0; pt < 4; pt++) {
                bf16x8 bX = *(const bf16x8*)(xb + (pt * 16 + col) * PROW + kk * 32 + quad * 8);
                acc[0][pt] = __builtin_amdgcn_mfma_f32_16x16x32_bf16(aW0, bX, acc[0][pt], 0, 0, 0);
                acc[1][pt] = __builtin_amdgcn_mfma_f32_16x16x32_bf16(aW1, bX, acc[1][pt], 0, 0, 0);
            }
        }
    }

#pragma unroll
    for (int pt = 0; pt < 4; pt++) {
        int p = pblk * 64 + pt * 16 + col;
        int s = p >> 3, n = p & 7;
        ushort* base = dst + ((size_t)(n * H_ + wave) * 2048 + s) * HD;
#pragma unroll
        for (int e = 0; e < 2; e++) {
            uint2 pk;
            pk.x = cvtpk(acc[e][pt][0], acc[e][pt][1]);
            pk.y = cvtpk(acc[e][pt][2], acc[e][pt][3]);
            *(uint2*)(base + e * 16 + quad * 4) = pk;
        }
    }
}

// ---------------------------------------------------------------------------
// Kernel 2: transpose V -> V^T.  v_ws[nh][key][32] bf16 -> vt_ws[nh][32][key].
// ---------------------------------------------------------------------------
__global__ __launch_bounds__(256) void vtrans_kernel(
    const ushort* __restrict__ v_ws, ushort* __restrict__ vt_ws)
{
    const int nh = blockIdx.x >> 4;
    const int slab = blockIdx.x & 15;
    __shared__ ushort t[HD][132];            // +4 pad
    const uint* src = (const uint*)(v_ws + ((size_t)nh * SK_ + slab * 128) * HD);
#pragma unroll
    for (int it = 0; it < 8; it++) {
        int i = it * 256 + threadIdx.x;      // 2048 uints = 128 keys x 16
        int key = i >> 4, j = i & 15;
        uint u = src[i];
        t[2 * j][key]     = (ushort)(u & 0xffffu);
        t[2 * j + 1][key] = (ushort)(u >> 16);
    }
    __syncthreads();
    uint* dst = (uint*)vt_ws;
#pragma unroll
    for (int it = 0; it < 8; it++) {
        int i = it * 256 + threadIdx.x;      // 2048 uints = 32 c x 64
        int c = i >> 6, kk = (i & 63) * 2;
        dst[(size_t)(nh * HD + c) * (SK_ / 2) + slab * 64 + (i & 63)] =
            (uint)t[c][kk] | ((uint)t[c][kk + 1] << 16);
    }
}

// ---------------------------------------------------------------------------
// Kernel 3: attention via MFMA 32x32x16 bf16 (T12 restructure).
// Wave tile = 32 q x 32 k.  Swapped QK^T: lane holds P[key=crow(r,hi)][q=lane&31].
// P -> PV B-frag via 8 cvt_pk + 4 permlane32_swap.
// K split across wave pairs (unnormalized exp is distributive); LDS combine.
// ---------------------------------------------------------------------------
__global__ __launch_bounds__(256) void attn_mfma(
    const ushort* __restrict__ q_ws, const ushort* __restrict__ k_ws,
    const ushort* __restrict__ vt_ws, ushort* __restrict__ x_ws)
{
    const int nh    = blockIdx.y;
    const int lane  = threadIdx.x & 63;
    const int wave  = threadIdx.x >> 6;
    const int tile  = wave >> 1;         // which 32-q tile of the block's 64
    const int khalf = wave & 1;          // [0,1024) or [1024,2048) keys
    const int row   = lane & 31;
    const int hi    = lane >> 5;
    const int qbase = blockIdx.x * 64 + tile * 32;

    // B-frag Q: lane holds Q[hd=hi*8+j][q=qbase+row], contiguous 16B loads.
    const ushort* qrow = q_ws + ((size_t)nh * SQ_ + qbase + row) * HD;
    const bf16x8 bQ0 = *(const bf16x8*)(qrow + hi * 8);
    const bf16x8 bQ1 = *(const bf16x8*)(qrow + 16 + hi * 8);

    const ushort* kb = k_ws  + (size_t)nh * SK_ * HD + (size_t)row * HD + hi * 8;
    const ushort* vb = vt_ws + (size_t)nh * HD * SK_ + (size_t)row * SK_ + hi * 8;

    f32x16 acc = {};
    float lsum = 0.f;

    const int kc0 = khalf * (SK_ / 2);
#pragma unroll 2
    for (int kc = kc0; kc < kc0 + SK_ / 2; kc += 32) {
        bf16x8 aK0 = *(const bf16x8*)(kb + (size_t)kc * HD);
        bf16x8 aK1 = *(const bf16x8*)(kb + (size_t)kc * HD + 16);
        bf16x8 aV0 = *(const bf16x8*)(vb + kc);
        bf16x8 aV1 = *(const bf16x8*)(vb + kc + 16);

        f32x16 S = {};
        S = __builtin_amdgcn_mfma_f32_32x32x16_bf16(aK0, bQ0, S, 0, 0, 0);
        S = __builtin_amdgcn_mfma_f32_32x32x16_bf16(aK1, bQ1, S, 0, 0, 0);

        // P[key][q] = 2^S  (log2e folded into Wq).  reg r -> key (r&3)+8*(r>>2)+4*hi.
        float p[16];
#pragma unroll
        for (int r = 0; r < 16; r++) p[r] = fexp2(S[r]);

        lsum += ((((p[0] + p[1]) + (p[2] + p[3])) + ((p[4] + p[5]) + (p[6] + p[7])))
               + (((p[8] + p[9]) + (p[10] + p[11])) + ((p[12] + p[13]) + (p[14] + p[15]))));

        // Build PV B-frags: word jw of frag needs keys (hi*8+2jw, hi*8+2jw+1).
        uint w0 = cvtpk(p[0], p[1]),   w2 = cvtpk(p[4], p[5]);
        uint w1 = cvtpk(p[2], p[3]),   w3 = cvtpk(p[6], p[7]);
        plswap(w0, w2);                // w0={lo(0,1),hi(8,9)}  w2={lo(4,5),hi(12,13)}
        plswap(w1, w3);                // w1={lo(2,3),hi(10,11)} w3={lo(6,7),hi(14,15)}
        uint w4 = cvtpk(p[8], p[9]),   w6 = cvtpk(p[12], p[13]);
        uint w5 = cvtpk(p[10], p[11]), w7 = cvtpk(p[14], p[15]);
        plswap(w4, w6);
        plswap(w5, w7);
        bf16x8 bP0 = __builtin_bit_cast(bf16x8, make_uint4(w0, w1, w2, w3));
        bf16x8 bP1 = __builtin_bit_cast(bf16x8, make_uint4(w4, w5, w6, w7));

        acc = __builtin_amdgcn_mfma_f32_32x32x16_bf16(aV0, bP0, acc, 0, 0, 0);
        acc = __builtin_amdgcn_mfma_f32_32x32x16_bf16(aV1, bP1, acc, 0, 0, 0);
    }

    // Combine the two K-halves (wave pairs) via LDS, then normalize + store.
    __shared__ float red[2][16][64];     // [tile][reg][lane] - conflict-free
    __shared__ float redl[2][64];
    if (khalf) {
#pragma unroll
        for (int r = 0; r < 16; r++) red[tile][r][lane] = acc[r];
        redl[tile][lane] = lsum;
    }
    __syncthreads();
    if (!khalf) {
#pragma unroll
        for (int r = 0; r < 16; r++) acc[r] += red[tile][r][lane];
        lsum += redl[tile][lane];
        lsum += __shfl_xor(lsum, 32, 64);   // lanes l, l^32 hold complementary keys
        const float inv = 1.f / lsum;

        const int n = nh >> 2, h = nh & 3;
        ushort* xo = x_ws + ((size_t)n * SQ_ + qbase + row) * INNER + h * HD;
#pragma unroll
        for (int rg = 0; rg < 4; rg++) {    // acc reg rg*4+t -> c = t + 8*rg + 4*hi
            uint2 pk;
            pk.x = cvtpk(acc[rg * 4 + 0] * inv, acc[rg * 4 + 1] * inv);
            pk.y = cvtpk(acc[rg * 4 + 2] * inv, acc[rg * 4 + 3] * inv);
            *(uint2*)(xo + rg * 8 + hi * 4) = pk;
        }
    }
}

// ---------------------------------------------------------------------------
// Kernel 4: up-projection via MFMA 16x16x32 bf16 (unchanged).
// ---------------------------------------------------------------------------
__global__ __launch_bounds__(256) void up_mfma(
    const ushort* __restrict__ x_ws, const ushort* __restrict__ wup_bf,
    float* __restrict__ out)
{
    const int pblk = blockIdx.x;
    const int dblk = blockIdx.y;
    const int wave = threadIdx.x >> 6, lane = threadIdx.x & 63;
    const int quad = lane >> 4, col = lane & 15;

    const int p0 = pblk * 64 + wave * 16;
    const ushort* xrow = x_ws + (size_t)(p0 + col) * INNER + quad * 8;
    bf16x8 bX[4];
#pragma unroll
    for (int kk = 0; kk < 4; kk++)
        bX[kk] = *(const bf16x8*)(xrow + kk * 32);

    const int p = p0 + col;
    const int n = p >> 11, s = p & 2047;        // x row p = n*2048 + s
    float* obase = out + ((size_t)s * NB + n) * DD;

#pragma unroll
    for (int mt = 0; mt < 4; mt++) {
        const int d0 = dblk * 64 + mt * 16;
        const ushort* wrow = wup_bf + (size_t)(d0 + col) * INNER + quad * 8;
        f32x4 acc = {0.f, 0.f, 0.f, 0.f};
#pragma unroll
        for (int kk = 0; kk < 4; kk++) {
            bf16x8 aW = *(const bf16x8*)(wrow + kk * 32);
            acc = __builtin_amdgcn_mfma_f32_16x16x32_bf16(aW, bX[kk], acc, 0, 0, 0);
        }
        *(float4*)(obase + d0 + quad * 4) = make_float4(acc[0], acc[1], acc[2], acc[3]);
    }
}

// ---------------------------------------------------------------------------
extern "C" void kernel_launch(void* const* d_in, const int* in_sizes, int n_in,
                              void* d_out, int out_size, void* d_ws, size_t ws_size,
                              hipStream_t stream)
{
    const float* query    = (const float*)d_in[0];
    const float* key_feat = (const float*)d_in[1];
    const float* Wq  = (const float*)d_in[2];
    const float* Wk  = (const float*)d_in[3];
    const float* Wv  = (const float*)d_in[4];
    const float* Wup = (const float*)d_in[5];
    float* out = (float*)d_out;

    ushort* ws16 = (ushort*)d_ws;
    const size_t SZ = (size_t)NB * H_ * 2048 * HD;   // 2,097,152 elems per tensor
    ushort* q_ws   = ws16;                           // bf16
    ushort* k_ws   = ws16 + SZ;                      // bf16
    ushort* v_ws   = ws16 + 2 * SZ;                  // bf16
    ushort* vt_ws  = ws16 + 3 * SZ;                  // bf16, transposed
    ushort* wbf    = vt_ws;                          // aliased: consumed by proj
                                                     // BEFORE vtrans overwrites
    ushort* x_ws   = ws16 + 4 * SZ;                  // bf16
    ushort* wup_bf = ws16 + 5 * SZ;                  // bf16, never aliased

    wprep_kernel<<<256, 256, 0, stream>>>(Wq, Wk, Wv, Wup, wbf, wup_bf);
    proj_mfma<<<dim3(256, 3), 256, 0, stream>>>(query, key_feat, wbf,
                                                q_ws, k_ws, v_ws);
    vtrans_kernel<<<512, 256, 0, stream>>>(v_ws, vt_ws);
    attn_mfma<<<dim3(SQ_ / 64, 32), 256, 0, stream>>>(q_ws, k_ws, vt_ws, x_ws);
    up_mfma<<<dim3(256, 16), 256, 0, stream>>>(x_ws, wup_bf, out);
}